// Round 1
// baseline (414.408 us; speedup 1.0000x reference)
//
#include <hip/hip_runtime.h>
#include <math.h>

#define Bn 512
#define Sn 1024
#define Tn 48

static constexpr float LOG2E = 1.4426950408889634f;
static constexpr float LN2f  = 0.6931471805599453f;

__device__ __forceinline__ float rlane(float x, int lane) {
  return __int_as_float(__builtin_amdgcn_readlane(__float_as_int(x), lane));
}

// One wave (64 lanes) per batch. Lane j (j<48) owns state j: score_j, row j of
// E = 2^(trans'[j,i] - mt_j) in 48 VGPRs. Per step: u_i = 2^(score_i - score_0)
// (one exp per lane), then v_j = sum_i E_ji * u_i via readlane-broadcast FMAs,
// score'_j = score_0 + mt_j + log2(v_j) + em'_j. All in log2 domain (inputs
// pre-scaled by log2e) so v_exp_f32 / v_log_f32 are used natively.
__global__ __launch_bounds__(64) void crf_fwd(
    const float* __restrict__ emissions,
    const int*   __restrict__ tags,
    const float* __restrict__ mask,
    const float* __restrict__ trans,
    const float* __restrict__ startt,
    const float* __restrict__ endt,
    float* __restrict__ per_batch)
{
  const int b  = blockIdx.x;
  const int j  = threadIdx.x;
  const int jc = (j < Tn) ? j : (Tn - 1);   // lanes 48..63 shadow lane 47 (results unused)

  const float* __restrict__ emb = emissions + (size_t)b * Sn * Tn;
  const int*   __restrict__ tgb = tags + (size_t)b * Sn;
  const float* __restrict__ mkb = mask + (size_t)b * Sn;

  // Constant per-lane data: row max and E row (log2 domain).
  float mt = -3.0e38f;
  #pragma unroll
  for (int i = 0; i < Tn; ++i) mt = fmaxf(mt, trans[jc*Tn + i]);
  const float mtp = mt * LOG2E;
  float E[Tn];
  #pragma unroll
  for (int i = 0; i < Tn; ++i)
    E[i] = __builtin_amdgcn_exp2f(fmaf(trans[jc*Tn + i], LOG2E, -mtp));

  const float em0  = emb[jc];
  const int   tag0 = tgb[0];
  float score = (startt[jc] + em0) * LOG2E;   // log2-scaled domain
  float numer = 0.0f;                          // natural domain
  if (j == tag0) numer += em0;
  if (j == 0)    numer += startt[tag0];
  int lt = tag0;

  auto do_step = [&](float em_raw, float mk, int tg, float tval) {
    const float m0 = rlane(score, 0);
    const float u  = __builtin_amdgcn_exp2f(score - m0);
    float a0 = 0.f, a1 = 0.f, a2 = 0.f, a3 = 0.f;
    #pragma unroll
    for (int i = 0; i < Tn; i += 4) {
      a0 = fmaf(rlane(u, i+0), E[i+0], a0);
      a1 = fmaf(rlane(u, i+1), E[i+1], a1);
      a2 = fmaf(rlane(u, i+2), E[i+2], a2);
      a3 = fmaf(rlane(u, i+3), E[i+3], a3);
    }
    const float v = (a0 + a1) + (a2 + a3);
    float nxt = m0 + mtp + __builtin_amdgcn_logf(v);
    nxt = fmaf(em_raw, LOG2E, nxt);
    const bool on = (mk > 0.0f);
    score = on ? nxt : score;
    float contrib = (j == tg) ? em_raw : 0.0f;
    if (j == 0) contrib += tval;
    numer = fmaf(mk, contrib, numer);
    lt = on ? tg : lt;
  };

  // Prologue: steps 1..3 (direct, unpipelined loads).
  #pragma unroll
  for (int s = 1; s < 4; ++s) {
    const float er = emb[s*Tn + jc];
    const float mk = mkb[s];
    const int   tg = tgb[s];
    const int   tp = tgb[s-1];
    const float tv = trans[tg*Tn + tp];
    do_step(er, mk, tg, tv);
  }

  // Preload chunk s0 = 4.
  float ec0 = emb[4*Tn + jc], ec1 = emb[5*Tn + jc],
        ec2 = emb[6*Tn + jc], ec3 = emb[7*Tn + jc];
  int4   tgc = *(const int4*)(tgb + 4);
  float4 mkc = *(const float4*)(mkb + 4);
  {
    const int ptail = tgb[3];
    // transitions lookups for the current chunk (L1/L2-hot, 9 KB table)
    ec0 = ec0; // no-op; keep structure clear
  }
  float tv0, tv1, tv2, tv3;
  {
    const int ptail = tgb[3];
    tv0 = trans[tgc.x*Tn + ptail];
    tv1 = trans[tgc.y*Tn + tgc.x];
    tv2 = trans[tgc.z*Tn + tgc.y];
    tv3 = trans[tgc.w*Tn + tgc.z];
  }

  // Pipelined main loop: process chunk s0, prefetch chunk s0+4.
  for (int s0 = 4; s0 + 4 < Sn; s0 += 4) {
    const int sn = s0 + 4;
    const float en0 = emb[(sn+0)*Tn + jc];
    const float en1 = emb[(sn+1)*Tn + jc];
    const float en2 = emb[(sn+2)*Tn + jc];
    const float en3 = emb[(sn+3)*Tn + jc];
    const int4   tgn = *(const int4*)(tgb + sn);
    const float4 mkn = *(const float4*)(mkb + sn);

    do_step(ec0, mkc.x, tgc.x, tv0);
    do_step(ec1, mkc.y, tgc.y, tv1);
    do_step(ec2, mkc.z, tgc.z, tv2);
    do_step(ec3, mkc.w, tgc.w, tv3);

    tv0 = trans[tgn.x*Tn + tgc.w];
    tv1 = trans[tgn.y*Tn + tgn.x];
    tv2 = trans[tgn.z*Tn + tgn.y];
    tv3 = trans[tgn.w*Tn + tgn.z];
    ec0 = en0; ec1 = en1; ec2 = en2; ec3 = en3;
    tgc = tgn; mkc = mkn;
  }
  // Tail chunk s0 = 1020 (steps 1020..1023).
  do_step(ec0, mkc.x, tgc.x, tv0);
  do_step(ec1, mkc.y, tgc.y, tv1);
  do_step(ec2, mkc.z, tgc.z, tv2);
  do_step(ec3, mkc.w, tgc.w, tv3);

  // Denominator: lse over j of (score + end'[j]), then back to natural log.
  float vfin = (j < Tn) ? fmaf(endt[jc], LOG2E, score) : -__builtin_inff();
  float mx = vfin;
  #pragma unroll
  for (int off = 32; off > 0; off >>= 1)
    mx = fmaxf(mx, __shfl_xor(mx, off));
  float p = (j < Tn) ? __builtin_amdgcn_exp2f(vfin - mx) : 0.0f;
  float sm = p;
  #pragma unroll
  for (int off = 32; off > 0; off >>= 1)
    sm += __shfl_xor(sm, off);
  const float den = (mx + __builtin_amdgcn_logf(sm)) * LN2f;

  // Numerator: reduce lane partials, add end term.
  float nm = numer;
  #pragma unroll
  for (int off = 32; off > 0; off >>= 1)
    nm += __shfl_xor(nm, off);

  if (j == 0) {
    nm += endt[lt];
    per_batch[b] = den - nm;
  }
}

__global__ __launch_bounds__(512) void reduce512(const float* __restrict__ pb,
                                                 float* __restrict__ out) {
  __shared__ float red[8];
  const int t = threadIdx.x;
  float v = pb[t];
  #pragma unroll
  for (int off = 32; off > 0; off >>= 1) v += __shfl_xor(v, off);
  if ((t & 63) == 0) red[t >> 6] = v;
  __syncthreads();
  if (t == 0) {
    float s = 0.f;
    #pragma unroll
    for (int w = 0; w < 8; ++w) s += red[w];
    out[0] = s * (1.0f / 512.0f);
  }
}

extern "C" void kernel_launch(void* const* d_in, const int* in_sizes, int n_in,
                              void* d_out, int out_size, void* d_ws, size_t ws_size,
                              hipStream_t stream) {
  const float* emissions = (const float*)d_in[0];
  const int*   tags      = (const int*)d_in[1];
  const float* mask      = (const float*)d_in[2];
  const float* trans     = (const float*)d_in[3];
  const float* startt    = (const float*)d_in[4];
  const float* endt      = (const float*)d_in[5];
  float* pb = (float*)d_ws;   // 512 floats of scratch

  crf_fwd<<<Bn, 64, 0, stream>>>(emissions, tags, mask, trans, startt, endt, pb);
  reduce512<<<1, 512, 0, stream>>>(pb, (float*)d_out);
}